// Round 5
// baseline (291.974 us; speedup 1.0000x reference)
//
#include <hip/hip_runtime.h>
#include <hip/hip_bf16.h>

// NAM_89739046683406: per-feature tiny MLP (B=32768, F=128, H=64)
// logit(b) = bias + sum_f [ relu(relu(x[b,f]*w1[f]+b1[f]) @ w2[f] + b2[f]) . w3[f] + b3[f] ]
// out = [1-sigmoid, sigmoid]
//
// R5: fully fused. One prep kernel (w2 -> bf16 MFMA-A-fragment order; x -> bf16
// xT8[fg][b][f8] packed layout), then ONE main kernel: each wave owns 16 batch
// rows, loops over all 128 features accumulating the logit in a register
// (no atomics, no logit buffer, no final kernel - sigmoid fused in epilogue).

#define B_SZ 32768
#define F_SZ 128
#define H_SZ 64

typedef short short8 __attribute__((ext_vector_type(8)));       // bf16 x8
typedef unsigned short ushort8 __attribute__((ext_vector_type(8)));
typedef float floatx4 __attribute__((ext_vector_type(4)));

// round-half-up bf16
__device__ __forceinline__ unsigned short f2bf(float f) {
    return (unsigned short)((__float_as_uint(f) + 0x8000u) >> 16);
}
__device__ __forceinline__ unsigned pkbf(float a, float b) {
    unsigned ua = __float_as_uint(a) + 0x8000u;
    unsigned ub = __float_as_uint(b) + 0x8000u;
    return (ua >> 16) | (ub & 0xFFFF0000u);
}

// ws layout: [0,1MB) w2bf fragments; [1MB, 9MB) xT8
#define WS_W2  0
#define WS_XT8 (1024 * 1024)

// ---- fused prep ----
// blocks [0,128): w2[f] fp32 -> bf16 A-fragments: chunk c=gt*2+ks, lane, elem j:
//   value = w2[f][k=(c&1)*32+(lane>>4)*8+j][g=(c>>1)*16+(lane&15)]
// blocks [128, 128+4096): x (B,F) fp32 -> xT8: element (b,f) at
//   xT8[((f>>3)*B + b)*8 + (f&7)]  (so one 16B load = 8 consecutive f for one b)
__global__ __launch_bounds__(256)
void nam_prep(const float* __restrict__ w2, const float* __restrict__ x,
              unsigned short* __restrict__ w2bf, unsigned short* __restrict__ xT8)
{
    __shared__ float t[32][33];
    if (blockIdx.x < F_SZ) {
        const int f = blockIdx.x;
        const float* w2f = w2 + (size_t)f * H_SZ * H_SZ;
        #pragma unroll
        for (int it = 0; it < 2; ++it) {
            int idx  = it * 256 + threadIdx.x;   // 0..511
            int c    = idx >> 6;
            int lane = idx & 63;
            int g    = (c >> 1) * 16 + (lane & 15);
            int k0   = (c & 1) * 32 + (lane >> 4) * 8;
            union { short8 s; unsigned u[4]; } o;
            #pragma unroll
            for (int jj = 0; jj < 4; ++jj) {
                float a = w2f[(k0 + 2 * jj)     * H_SZ + g];
                float b = w2f[(k0 + 2 * jj + 1) * H_SZ + g];
                o.u[jj] = pkbf(a, b);
            }
            *(short8*)(w2bf + (size_t)f * 4096 + idx * 8) = o.s;
        }
        return;
    }
    // x -> xT8 via 32x32 LDS tile
    const int i  = blockIdx.x - F_SZ;
    const int bB = i & (B_SZ / 32 - 1);   // 0..1023
    const int bF = i >> 10;               // 0..3
    const int tx = threadIdx.x & 31, ty = threadIdx.x >> 5;   // ty 0..7
    #pragma unroll
    for (int k = 0; k < 4; ++k)
        t[ty + 8 * k][tx] = x[(size_t)(bB * 32 + ty + 8 * k) * F_SZ + bF * 32 + tx];
    __syncthreads();
    if (threadIdx.x < 128) {
        const int fgl = threadIdx.x >> 5;   // 0..3
        const int bl  = threadIdx.x & 31;
        unsigned r[4];
        #pragma unroll
        for (int k = 0; k < 4; ++k)
            r[k] = pkbf(t[bl][fgl * 8 + 2 * k], t[bl][fgl * 8 + 2 * k + 1]);
        const int fg = bF * 4 + fgl;
        *(uint4*)(xT8 + ((size_t)fg * B_SZ + bB * 32 + bl) * 8) =
            make_uint4(r[0], r[1], r[2], r[3]);
    }
}

// ---- fused main: one wave = 16 rows, loop over all 128 features ----
__global__ __launch_bounds__(256, 2)
void nam_fused(const ushort8* __restrict__ xT8,
               const float* __restrict__ w1, const float* __restrict__ b1,
               const float* __restrict__ b2, const float* __restrict__ w3,
               const float* __restrict__ b3, const float* __restrict__ bias,
               const unsigned short* __restrict__ w2bf,
               float* __restrict__ out)
{
    const int tid  = threadIdx.x;
    const int lane = tid & 63;
    const int wv   = tid >> 6;
    const int l15  = lane & 15;
    const int quad = lane >> 4;
    const int r0   = blockIdx.x * 64 + wv * 16;
    const int row  = r0 + l15;

    // wave-wide sum of b3 (added once at the end)
    float sb3 = b3[lane] + b3[lane + 64];
    #pragma unroll
    for (int m = 1; m < 64; m <<= 1) sb3 += __shfl_xor(sb3, m, 64);

    float s = 0.0f;

    for (int fg = 0; fg < F_SZ / 8; ++fg) {
        ushort8 xv8 = xT8[fg * B_SZ + row];     // x[row][fg*8 .. fg*8+7]
        #pragma unroll
        for (int f8 = 0; f8 < 8; ++f8) {
            const int f = fg * 8 + f8;
            const float xf = __uint_as_float(((unsigned)xv8[f8]) << 16);

            // w2 A-fragments: 8 coalesced 16B loads (L1/L2-hot, shared by all waves)
            const short8* wp = (const short8*)(w2bf + (size_t)f * 4096);
            short8 wfrag[4][2];
            #pragma unroll
            for (int gt = 0; gt < 4; ++gt)
                #pragma unroll
                for (int ks = 0; ks < 2; ++ks)
                    wfrag[gt][ks] = wp[(gt * 2 + ks) * 64 + lane];

            // layer 1 -> h1 B-fragment: B[k=quad*8+j][n=l15]
            short8 hfrag[2];
            #pragma unroll
            for (int ks = 0; ks < 2; ++ks) {
                const float4* w1p = (const float4*)(w1 + f * H_SZ + ks * 32 + quad * 8);
                const float4* b1p = (const float4*)(b1 + f * H_SZ + ks * 32 + quad * 8);
                float wk[8], bk[8];
                *(float4*)&wk[0] = w1p[0]; *(float4*)&wk[4] = w1p[1];
                *(float4*)&bk[0] = b1p[0]; *(float4*)&bk[4] = b1p[1];
                union { short8 s; unsigned u[4]; } o;
                #pragma unroll
                for (int jj = 0; jj < 4; ++jj) {
                    float h0 = fmaxf(fmaf(xf, wk[2 * jj],     bk[2 * jj]),     0.0f);
                    float h1 = fmaxf(fmaf(xf, wk[2 * jj + 1], bk[2 * jj + 1]), 0.0f);
                    o.u[jj] = pkbf(h0, h1);
                }
                hfrag[ks] = o.s;
            }

            // MFMA: D[g][b] = sum_h w2[h][g] * h1[b][h]
            floatx4 acc[4];
            #pragma unroll
            for (int gt = 0; gt < 4; ++gt) acc[gt] = (floatx4)(0.0f);
            #pragma unroll
            for (int ks = 0; ks < 2; ++ks)
                #pragma unroll
                for (int gt = 0; gt < 4; ++gt)
                    acc[gt] = __builtin_amdgcn_mfma_f32_16x16x32_bf16(
                        wfrag[gt][ks], hfrag[ks], acc[gt], 0, 0, 0);

            // epilogue: +b2, relu, .w3, accumulate into s
            // D layout: g = gt*16 + quad*4 + i, b = l15
            #pragma unroll
            for (int gt = 0; gt < 4; ++gt) {
                float4 b2v = *(const float4*)(b2 + f * H_SZ + gt * 16 + quad * 4);
                float4 w3v = *(const float4*)(w3 + f * H_SZ + gt * 16 + quad * 4);
                float b2a[4] = {b2v.x, b2v.y, b2v.z, b2v.w};
                float w3a[4] = {w3v.x, w3v.y, w3v.z, w3v.w};
                #pragma unroll
                for (int i = 0; i < 4; ++i)
                    s = fmaf(fmaxf(acc[gt][i] + b2a[i], 0.0f), w3a[i], s);
            }
        }
    }

    // reduce across quads (b = l15 fixed): 2 butterfly steps
    s += __shfl_xor(s, 16, 64);
    s += __shfl_xor(s, 32, 64);
    s += sb3 + bias[0];
    float p = 1.0f / (1.0f + __expf(-s));
    if (quad == 0)
        ((float2*)out)[row] = make_float2(1.0f - p, p);
}

extern "C" void kernel_launch(void* const* d_in, const int* in_sizes, int n_in,
                              void* d_out, int out_size, void* d_ws, size_t ws_size,
                              hipStream_t stream)
{
    const float* x    = (const float*)d_in[0];
    const float* w1   = (const float*)d_in[1];
    const float* b1   = (const float*)d_in[2];
    const float* w2   = (const float*)d_in[3];
    const float* b2   = (const float*)d_in[4];
    const float* w3   = (const float*)d_in[5];
    const float* b3   = (const float*)d_in[6];
    const float* bias = (const float*)d_in[7];
    float* out = (float*)d_out;

    unsigned short* w2bf = (unsigned short*)((char*)d_ws + WS_W2);
    unsigned short* xT8  = (unsigned short*)((char*)d_ws + WS_XT8);

    nam_prep<<<dim3(F_SZ + (B_SZ / 32) * (F_SZ / 32)), dim3(256), 0, stream>>>(
        w2, x, w2bf, xT8);
    nam_fused<<<dim3(B_SZ / 64), dim3(256), 0, stream>>>(
        (const ushort8*)xT8, w1, b1, b2, w3, b3, bias, w2bf, out);
}

// Round 9
// 247.842 us; speedup vs baseline: 1.1781x; 1.1781x over previous
//
#include <hip/hip_runtime.h>
#include <hip/hip_bf16.h>

// NAM_89739046683406: per-feature tiny MLP (B=32768, F=128, H=64)
// logit(b) = bias + sum_f [ relu(relu(x[b,f]*w1[f]+b1[f]) @ w2[f] + b2[f]) . w3[f] + b3[f] ]
// out = [1-sigmoid, sigmoid]
//
// R9 == R7 algorithm with the two never-validated constructs reverted to the
// forms proven on this container (R1/R4/R5 all ran): __float22bfloat162_rn ->
// pkbf shift-pack, __launch_bounds__(256,6) -> (256,4). Structure: prep w2 ->
// bf16 MFMA A-fragment order (ws, 1MB); main: one block = 16 batch rows (x
// staged coalesced into LDS), 4 waves each covering 32 features; per-row logit
// partial in a register; quad butterfly + LDS reduce; sigmoid fused.

#define B_SZ 32768
#define F_SZ 128
#define H_SZ 64

typedef short short8 __attribute__((ext_vector_type(8)));   // bf16 x8
typedef float floatx4 __attribute__((ext_vector_type(4)));  // fp32 x4 acc

__device__ __forceinline__ unsigned pkbf(float a, float b) {
    unsigned ua = __float_as_uint(a) + 0x8000u;
    unsigned ub = __float_as_uint(b) + 0x8000u;
    return (ua >> 16) | (ub & 0xFFFF0000u);
}

// ---- prep: w2[f] fp32 -> bf16 A-fragments ----
// chunk c = gt*2+ks; lane; elem j: value = w2[f][k=(c&1)*32+(lane>>4)*8+j][g=(c>>1)*16+(lane&15)]
__global__ __launch_bounds__(256)
void nam_prep_w2(const float* __restrict__ w2, unsigned short* __restrict__ w2bf)
{
    const int f = blockIdx.x;
    const float* w2f = w2 + (size_t)f * H_SZ * H_SZ;
    #pragma unroll
    for (int it = 0; it < 2; ++it) {
        int idx  = it * 256 + threadIdx.x;   // 0..511
        int c    = idx >> 6;
        int lane = idx & 63;
        int g    = (c >> 1) * 16 + (lane & 15);
        int k0   = (c & 1) * 32 + (lane >> 4) * 8;
        union { short8 s; unsigned u[4]; } o;
        #pragma unroll
        for (int jj = 0; jj < 4; ++jj) {
            float a = w2f[(k0 + 2 * jj)     * H_SZ + g];
            float b = w2f[(k0 + 2 * jj + 1) * H_SZ + g];
            o.u[jj] = pkbf(a, b);
        }
        *(short8*)(w2bf + (size_t)f * 4096 + idx * 8) = o.s;
    }
}

// ---- main: block = 16 rows; wave w covers f in [32w, 32w+32) ----
__global__ __launch_bounds__(256, 4)
void nam_fused(const float* __restrict__ x,
               const float* __restrict__ w1, const float* __restrict__ b1,
               const float* __restrict__ b2, const float* __restrict__ w3,
               const float* __restrict__ b3, const float* __restrict__ bias,
               const unsigned short* __restrict__ w2bf,
               float* __restrict__ out)
{
    __shared__ float xs[16 * 132];      // 16 rows x 128 f, row stride 132
    __shared__ float partial[4][16];

    const int tid  = threadIdx.x;
    const int lane = tid & 63;
    const int wv   = tid >> 6;
    const int l15  = lane & 15;
    const int quad = lane >> 4;
    const int r0   = blockIdx.x * 16;

    // stage x rows [r0, r0+16): contiguous 8KB = 512 float4, fully coalesced
    const float4* xg = (const float4*)(x + (size_t)r0 * F_SZ);
    #pragma unroll
    for (int it = 0; it < 2; ++it) {
        int g   = it * 256 + tid;       // float4 index 0..511
        int row = g >> 5;               // 32 float4 per row -> row 0..15
        int col = (g & 31) * 4;
        *(float4*)&xs[row * 132 + col] = xg[g];
    }

    // this wave's b3 subtotal (32 features, value replicated in both halves)
    float sb3 = b3[wv * 32 + (lane & 31)];
    sb3 += __shfl_xor(sb3, 1, 64);
    sb3 += __shfl_xor(sb3, 2, 64);
    sb3 += __shfl_xor(sb3, 4, 64);
    sb3 += __shfl_xor(sb3, 8, 64);
    sb3 += __shfl_xor(sb3, 16, 64);

    __syncthreads();

    const int f0 = wv * 32;
    const short8* wp = (const short8*)(w2bf + (size_t)f0 * 4096) + lane;

    float s = 0.0f;
    for (int fi = 0; fi < 32; ++fi) {
        const int f = f0 + fi;
        const float xf = xs[l15 * 132 + f];

        // w2 A-fragments: 8 coalesced 16B loads (L2-hot, 1MB table)
        short8 wfrag[4][2];
        #pragma unroll
        for (int gt = 0; gt < 4; ++gt)
            #pragma unroll
            for (int ks = 0; ks < 2; ++ks)
                wfrag[gt][ks] = wp[fi * 512 + (gt * 2 + ks) * 64];

        // layer 1 -> h1 B-fragment: B[k=quad*8+j][n=l15]
        short8 hfrag[2];
        #pragma unroll
        for (int ks = 0; ks < 2; ++ks) {
            const float4* wq = (const float4*)w1 + (size_t)f * 16 + ks * 8 + quad * 2;
            const float4* bq = (const float4*)b1 + (size_t)f * 16 + ks * 8 + quad * 2;
            float wk[8], bk[8];
            *(float4*)&wk[0] = wq[0]; *(float4*)&wk[4] = wq[1];
            *(float4*)&bk[0] = bq[0]; *(float4*)&bk[4] = bq[1];
            union { short8 s8; unsigned u[4]; } o;
            #pragma unroll
            for (int jj = 0; jj < 4; ++jj) {
                float h0 = fmaxf(fmaf(xf, wk[2 * jj],     bk[2 * jj]),     0.0f);
                float h1 = fmaxf(fmaf(xf, wk[2 * jj + 1], bk[2 * jj + 1]), 0.0f);
                o.u[jj] = pkbf(h0, h1);
            }
            hfrag[ks] = o.s8;
        }

        // acc init = b2 (folds the bias add into MFMA C)
        floatx4 acc[4];
        #pragma unroll
        for (int gt = 0; gt < 4; ++gt) {
            float4 bv = *((const float4*)b2 + (size_t)f * 16 + gt * 4 + quad);
            acc[gt] = floatx4{bv.x, bv.y, bv.z, bv.w};
        }

        // MFMA: D[g][b] = b2 + sum_h w2[h][g] * h1[b][h]
        #pragma unroll
        for (int ks = 0; ks < 2; ++ks)
            #pragma unroll
            for (int gt = 0; gt < 4; ++gt)
                acc[gt] = __builtin_amdgcn_mfma_f32_16x16x32_bf16(
                    wfrag[gt][ks], hfrag[ks], acc[gt], 0, 0, 0);

        // epilogue: relu, .w3 ; D layout: g = gt*16 + quad*4 + i, b = l15
        #pragma unroll
        for (int gt = 0; gt < 4; ++gt) {
            float4 wv3 = *((const float4*)w3 + (size_t)f * 16 + gt * 4 + quad);
            s = fmaf(fmaxf(acc[gt][0], 0.0f), wv3.x, s);
            s = fmaf(fmaxf(acc[gt][1], 0.0f), wv3.y, s);
            s = fmaf(fmaxf(acc[gt][2], 0.0f), wv3.z, s);
            s = fmaf(fmaxf(acc[gt][3], 0.0f), wv3.w, s);
        }
    }

    // reduce across quads (row = l15), then across waves via LDS
    s += __shfl_xor(s, 16, 64);
    s += __shfl_xor(s, 32, 64);
    if (quad == 0) partial[wv][l15] = s + sb3;
    __syncthreads();
    if (tid < 16) {
        float t = partial[0][tid] + partial[1][tid] + partial[2][tid]
                + partial[3][tid] + bias[0];
        float p = 1.0f / (1.0f + __expf(-t));
        ((float2*)out)[r0 + tid] = make_float2(1.0f - p, p);
    }
}

extern "C" void kernel_launch(void* const* d_in, const int* in_sizes, int n_in,
                              void* d_out, int out_size, void* d_ws, size_t ws_size,
                              hipStream_t stream)
{
    const float* x    = (const float*)d_in[0];
    const float* w1   = (const float*)d_in[1];
    const float* b1   = (const float*)d_in[2];
    const float* w2   = (const float*)d_in[3];
    const float* b2   = (const float*)d_in[4];
    const float* w3   = (const float*)d_in[5];
    const float* b3   = (const float*)d_in[6];
    const float* bias = (const float*)d_in[7];
    float* out = (float*)d_out;

    unsigned short* w2bf = (unsigned short*)d_ws;

    nam_prep_w2<<<dim3(F_SZ), dim3(256), 0, stream>>>(w2, w2bf);
    nam_fused<<<dim3(B_SZ / 16), dim3(256), 0, stream>>>(
        x, w1, b1, b2, w3, b3, bias, w2bf, out);
}

// Round 11
// 147.519 us; speedup vs baseline: 1.9792x; 1.6801x over previous
//
#include <hip/hip_runtime.h>
#include <hip/hip_bf16.h>

// NAM_89739046683406: per-feature tiny MLP (B=32768, F=128, H=64)
// logit(b) = bias + sum_f [ relu(relu(x[b,f]*w1[f]+b1[f]) @ w2[f] + b2[f]) . w3[f] + b3[f] ]
// out = [1-sigmoid, sigmoid]
//
// R11 = R10 with (a) pkbf reverted to the R9-proven shift/or form (v_perm was
// the only never-validated construct in the diverging build), (b) the fi-loop
// pinned to unroll 1 so the ~116-VGPR live set cannot blow past the
// launch_bounds(512,4) 128-VGPR cap (suspected spill-thrash caused 145us).
// Structure: prep packs w2 -> bf16 MFMA A-fragment order (1MB) + w1b1/b2w3
// bf16 tables (64KB); main: block = 64 rows x 512 thr, 8 waves each covering
// 16 features with 4 B-fragments (64 rows) per MFMA step; no atomics; quad
// butterfly + LDS reduce; sigmoid fused.

#define B_SZ 32768
#define F_SZ 128
#define H_SZ 64

typedef short short8 __attribute__((ext_vector_type(8)));   // bf16 x8
typedef float floatx4 __attribute__((ext_vector_type(4)));  // fp32 x4 acc

// round-half-up bf16 pair-pack (R9-proven form)
__device__ __forceinline__ unsigned pkbf(float lo, float hi) {
    unsigned ua = __float_as_uint(lo) + 0x8000u;
    unsigned ub = __float_as_uint(hi) + 0x8000u;
    return (ua >> 16) | (ub & 0xFFFF0000u);
}
__device__ __forceinline__ float bf2f(unsigned short u) {
    return __uint_as_float(((unsigned)u) << 16);
}

// ws (shorts): [0, 524288) w2 frags; [524288, +16384) w1b1; [+16384, +16384) b2w3
#define WS_W1B1 524288
#define WS_B2W3 (524288 + 16384)

// ---- prep: pack all tables to bf16 ----
// blocks [0,128): w2[f] -> A-fragment order (unit idx = c*64+lane; c = gt*2+ks;
//   value = w2[f][k=(c&1)*32+(lane>>4)*8+j][g=(c>>1)*16+(lane&15)])
// block 128: w1b1[f][ks][w1:32 shorts | b1:32 shorts], short idx in sect = quad*8+j
// block 129: b2w3[f][gt][quad][b2:4 | w3:4]
__global__ __launch_bounds__(256)
void nam_prep(const float* __restrict__ w2, const float* __restrict__ w1,
              const float* __restrict__ b1, const float* __restrict__ b2,
              const float* __restrict__ w3, unsigned short* __restrict__ ws)
{
    const int bx = blockIdx.x, tid = threadIdx.x;
    unsigned* w2p  = (unsigned*)ws;
    unsigned* w1b1 = (unsigned*)(ws + WS_W1B1);
    unsigned* b2w3 = (unsigned*)(ws + WS_B2W3);
    if (bx < 128) {
        const float* w2f = w2 + (size_t)bx * 4096;
        #pragma unroll
        for (int it = 0; it < 2; ++it) {
            int idx  = it * 256 + tid;       // short8 unit 0..511
            int c    = idx >> 6;
            int lane = idx & 63;
            int g    = (c >> 1) * 16 + (lane & 15);
            int k0   = (c & 1) * 32 + (lane >> 4) * 8;
            unsigned o0 = pkbf(w2f[(k0 + 0) * 64 + g], w2f[(k0 + 1) * 64 + g]);
            unsigned o1 = pkbf(w2f[(k0 + 2) * 64 + g], w2f[(k0 + 3) * 64 + g]);
            unsigned o2 = pkbf(w2f[(k0 + 4) * 64 + g], w2f[(k0 + 5) * 64 + g]);
            unsigned o3 = pkbf(w2f[(k0 + 6) * 64 + g], w2f[(k0 + 7) * 64 + g]);
            *(uint4*)(w2p + ((size_t)bx * 512 + idx) * 4) = make_uint4(o0, o1, o2, o3);
        }
    } else if (bx == 128) {
        #pragma unroll
        for (int i = 0; i < 32; ++i) {
            int u = tid + 256 * i;           // u32 idx 0..8191
            int f = u >> 6, r = u & 63, ks = r >> 5, h = r & 31;
            int isb = h >> 4, t4 = h & 15;
            const float* src = (isb ? b1 : w1) + f * 64 + ks * 32 + t4 * 2;
            w1b1[u] = pkbf(src[0], src[1]);
        }
    } else {
        #pragma unroll
        for (int i = 0; i < 32; ++i) {
            int u = tid + 256 * i;           // u32 idx 0..8191
            int f = u >> 6, r = u & 63, gt = r >> 4, q = (r >> 2) & 3, e = r & 3;
            const float* src = ((e < 2) ? b2 : w3) + f * 64 + gt * 16 + q * 4 + (e & 1) * 2;
            b2w3[u] = pkbf(src[0], src[1]);
        }
    }
}

// ---- main: block = 64 rows, 8 waves; wave w covers f in [16w, 16w+16) ----
__global__ __launch_bounds__(512, 4)
void nam_fused(const float* __restrict__ x, const float* __restrict__ b3,
               const float* __restrict__ bias,
               const unsigned short* __restrict__ ws,
               float* __restrict__ out)
{
    __shared__ float xs[64 * 132];       // 64 rows x 128 f, stride 132
    __shared__ float partial[8][64];

    const int tid  = threadIdx.x;
    const int lane = tid & 63;
    const int wv   = tid >> 6;           // 0..7
    const int l15  = lane & 15;
    const int quad = lane >> 4;
    const int r0   = blockIdx.x * 64;

    // stage x rows [r0, r0+64): contiguous 32KB = 2048 float4, coalesced
    const float4* xg = (const float4*)(x + (size_t)r0 * F_SZ);
    #pragma unroll
    for (int it = 0; it < 4; ++it) {
        int g   = it * 512 + tid;        // 0..2047
        int row = g >> 5;                // 0..63
        int col = (g & 31) * 4;
        *(float4*)&xs[row * 132 + col] = xg[g];
    }

    // wave's b3 subtotal over its 16 features (replicated across quads)
    float sb3 = b3[wv * 16 + l15];
    sb3 += __shfl_xor(sb3, 1, 64);
    sb3 += __shfl_xor(sb3, 2, 64);
    sb3 += __shfl_xor(sb3, 4, 64);
    sb3 += __shfl_xor(sb3, 8, 64);

    __syncthreads();

    const short8* wp  = (const short8*)ws;               // w2 frags: f*512 + c*64 + lane
    const short8* wbp = (const short8*)(ws + WS_W1B1);   // w1b1: f*16 + ks*8 + (b1?4:0) + quad
    const short8* bwp = (const short8*)(ws + WS_B2W3);   // b2w3: f*16 + gt*4 + quad

    const int f0 = wv * 16;
    float s[4] = {0.0f, 0.0f, 0.0f, 0.0f};

    #pragma unroll 1
    for (int fi = 0; fi < 16; ++fi) {
        const int f = f0 + fi;

        float xf[4];
        #pragma unroll
        for (int bt = 0; bt < 4; ++bt) xf[bt] = xs[(bt * 16 + l15) * 132 + f];

        // layer 1 -> h1 B-fragments: B[k=quad*8+j][n=bt*16+l15]
        short8 hfrag[4][2];
        #pragma unroll
        for (int ks = 0; ks < 2; ++ks) {
            short8 w1s = wbp[f * 16 + ks * 8 + quad];
            short8 b1s = wbp[f * 16 + ks * 8 + 4 + quad];
            float wk[8], bk[8];
            #pragma unroll
            for (int j = 0; j < 8; ++j) {
                wk[j] = bf2f((unsigned short)w1s[j]);
                bk[j] = bf2f((unsigned short)b1s[j]);
            }
            #pragma unroll
            for (int bt = 0; bt < 4; ++bt) {
                union { short8 s8; unsigned u[4]; } o;
                #pragma unroll
                for (int t = 0; t < 4; ++t) {
                    float h0 = fmaxf(fmaf(xf[bt], wk[2 * t],     bk[2 * t]),     0.0f);
                    float h1 = fmaxf(fmaf(xf[bt], wk[2 * t + 1], bk[2 * t + 1]), 0.0f);
                    o.u[t] = pkbf(h0, h1);
                }
                hfrag[bt][ks] = o.s8;
            }
        }

        // w2 A-fragments: 8 coalesced 16B loads
        short8 wfrag[4][2];
        #pragma unroll
        for (int gt = 0; gt < 4; ++gt)
            #pragma unroll
            for (int ks = 0; ks < 2; ++ks)
                wfrag[gt][ks] = wp[f * 512 + (gt * 2 + ks) * 64 + lane];

        // MFMA + epilogue; D layout: g = gt*16 + quad*4 + i, n = bt*16 + l15
        #pragma unroll
        for (int gt = 0; gt < 4; ++gt) {
            short8 bw = bwp[f * 16 + gt * 4 + quad];
            float b2f[4], w3f[4];
            #pragma unroll
            for (int i = 0; i < 4; ++i) {
                b2f[i] = bf2f((unsigned short)bw[i]);
                w3f[i] = bf2f((unsigned short)bw[4 + i]);
            }
            #pragma unroll
            for (int bt = 0; bt < 4; ++bt) {
                floatx4 acc = {b2f[0], b2f[1], b2f[2], b2f[3]};
                acc = __builtin_amdgcn_mfma_f32_16x16x32_bf16(
                    wfrag[gt][0], hfrag[bt][0], acc, 0, 0, 0);
                acc = __builtin_amdgcn_mfma_f32_16x16x32_bf16(
                    wfrag[gt][1], hfrag[bt][1], acc, 0, 0, 0);
                #pragma unroll
                for (int i = 0; i < 4; ++i)
                    s[bt] = fmaf(fmaxf(acc[i], 0.0f), w3f[i], s[bt]);
            }
        }
    }

    // reduce across quads, publish per-wave partials
    #pragma unroll
    for (int bt = 0; bt < 4; ++bt) {
        s[bt] += __shfl_xor(s[bt], 16, 64);
        s[bt] += __shfl_xor(s[bt], 32, 64);
    }
    if (quad == 0) {
        #pragma unroll
        for (int bt = 0; bt < 4; ++bt)
            partial[wv][bt * 16 + l15] = s[bt] + sb3;
    }
    __syncthreads();
    if (tid < 64) {
        float t = bias[0];
        #pragma unroll
        for (int w = 0; w < 8; ++w) t += partial[w][tid];
        float p = 1.0f / (1.0f + __expf(-t));
        ((float2*)out)[r0 + tid] = make_float2(1.0f - p, p);
    }
}

extern "C" void kernel_launch(void* const* d_in, const int* in_sizes, int n_in,
                              void* d_out, int out_size, void* d_ws, size_t ws_size,
                              hipStream_t stream)
{
    const float* x    = (const float*)d_in[0];
    const float* w1   = (const float*)d_in[1];
    const float* b1   = (const float*)d_in[2];
    const float* w2   = (const float*)d_in[3];
    const float* b2   = (const float*)d_in[4];
    const float* w3   = (const float*)d_in[5];
    const float* b3   = (const float*)d_in[6];
    const float* bias = (const float*)d_in[7];
    float* out = (float*)d_out;

    unsigned short* ws = (unsigned short*)d_ws;

    nam_prep<<<dim3(130), dim3(256), 0, stream>>>(w2, w1, b1, b2, w3, ws);
    nam_fused<<<dim3(B_SZ / 64), dim3(512), 0, stream>>>(x, b3, bias, ws, out);
}

// Round 12
// 130.603 us; speedup vs baseline: 2.2356x; 1.1295x over previous
//
#include <hip/hip_runtime.h>
#include <hip/hip_bf16.h>

// NAM_89739046683406: per-feature tiny MLP (B=32768, F=128, H=64)
// logit(b) = bias + sum_f [ relu(relu(x[b,f]*w1[f]+b1[f]) @ w2[f] + b2[f]) . w3[f] + b3[f] ]
// out = [1-sigmoid, sigmoid]
//
// R12: f-OUTER structure. Wave = 1 feature x 1024 rows; all per-f weights
// (w2 MFMA A-fragments, w1/b1/b2/w3) live in registers for the whole wave ->
// per-chunk memory traffic is ONE x load. Block = 4 waves = 4 features x 1024
// rows; LDS partial[4][1024] + block reduce -> 1 atomicAdd per (row, 4f-group).
// Prep packs w2 -> bf16 fragment order (grid-strided, uniform) and zeroes the
// logit buffer. Final kernel applies bias + sigmoid.

#define B_SZ 32768
#define F_SZ 128
#define H_SZ 64

typedef short short8 __attribute__((ext_vector_type(8)));   // bf16 x8
typedef float floatx4 __attribute__((ext_vector_type(4)));  // fp32 x4 acc

// round-half-up bf16 pair-pack (R9/R11-proven form)
__device__ __forceinline__ unsigned pkbf(float lo, float hi) {
    unsigned ua = __float_as_uint(lo) + 0x8000u;
    unsigned ub = __float_as_uint(hi) + 0x8000u;
    return (ua >> 16) | (ub & 0xFFFF0000u);
}

// ws layout (bytes): [0, 1MB) w2bf fragment table; [1MB, 1MB+128KB) logit
#define WS_LOG_SHORTS 524288

// ---- prep: blocks [0,256) pack w2 -> A-fragment order (grid-strided, uniform)
//      blocks [256,288) zero the logit buffer
// fragment layout: per f, unit idx = c*64+lane (c = gt*2+ks):
//   value = w2[f][k=(c&1)*32+(lane>>4)*8+j][g=(c>>1)*16+(lane&15)], j=0..7
__global__ __launch_bounds__(256)
void nam_prep(const float* __restrict__ w2, unsigned short* __restrict__ ws)
{
    const int bx = blockIdx.x, tid = threadIdx.x;
    if (bx < 256) {
        int unit = bx * 256 + tid;        // 0..65535
        int f    = unit >> 9;             // 0..127
        int idx  = unit & 511;
        int c    = idx >> 6;
        int lane = idx & 63;
        int g    = (c >> 1) * 16 + (lane & 15);
        int k0   = (c & 1) * 32 + (lane >> 4) * 8;
        const float* w2f = w2 + (size_t)f * 4096;
        unsigned o0 = pkbf(w2f[(k0 + 0) * 64 + g], w2f[(k0 + 1) * 64 + g]);
        unsigned o1 = pkbf(w2f[(k0 + 2) * 64 + g], w2f[(k0 + 3) * 64 + g]);
        unsigned o2 = pkbf(w2f[(k0 + 4) * 64 + g], w2f[(k0 + 5) * 64 + g]);
        unsigned o3 = pkbf(w2f[(k0 + 6) * 64 + g], w2f[(k0 + 7) * 64 + g]);
        *(uint4*)((unsigned*)ws + ((size_t)f * 512 + idx) * 4) =
            make_uint4(o0, o1, o2, o3);
    } else {
        float4* logit4 = (float4*)(ws + WS_LOG_SHORTS);
        logit4[(bx - 256) * 256 + tid] = make_float4(0.f, 0.f, 0.f, 0.f);
    }
}

// ---- main: block = 4 waves; wave wv owns feature f = (bx>>5)*4+wv,
//      rows [rg*1024, rg*1024+1024), rg = bx&31 (consecutive blocks -> different
//      logit lines, same w2 tables). 16 chunks of 64 rows.
__global__ __launch_bounds__(256, 3)
void nam_main(const float* __restrict__ x,
              const float* __restrict__ w1, const float* __restrict__ b1,
              const float* __restrict__ b2, const float* __restrict__ w3,
              const float* __restrict__ b3,
              const unsigned short* __restrict__ ws,
              float* __restrict__ logit)
{
    __shared__ float partial[4][1024];   // 16KB

    const int tid  = threadIdx.x;
    const int lane = tid & 63;
    const int wv   = tid >> 6;           // 0..3
    const int l15  = lane & 15;
    const int quad = lane >> 4;
    const int rg   = blockIdx.x & 31;
    const int gf   = blockIdx.x >> 5;    // 0..31
    const int f    = gf * 4 + wv;
    const int rb   = rg * 1024;

    // ---- per-wave resident tables ----
    // w2 A-fragments (8 x 16B coalesced loads)
    const short8* wp = (const short8*)ws + (size_t)f * 512 + lane;
    short8 wfrag[4][2];
    #pragma unroll
    for (int gt = 0; gt < 4; ++gt)
        #pragma unroll
        for (int ks = 0; ks < 2; ++ks)
            wfrag[gt][ks] = wp[(gt * 2 + ks) * 64];

    // w1/b1 fp32: element k = ks*32 + quad*8 + j
    float wk[2][8], bk[2][8];
    #pragma unroll
    for (int ks = 0; ks < 2; ++ks) {
        const float4* wq = (const float4*)(w1 + f * 64 + ks * 32 + quad * 8);
        const float4* bq = (const float4*)(b1 + f * 64 + ks * 32 + quad * 8);
        *(float4*)&wk[ks][0] = wq[0]; *(float4*)&wk[ks][4] = wq[1];
        *(float4*)&bk[ks][0] = bq[0]; *(float4*)&bk[ks][4] = bq[1];
    }

    // b2/w3 fp32: element g = gt*16 + quad*4 + i
    float b2f[4][4], w3f[4][4];
    #pragma unroll
    for (int gt = 0; gt < 4; ++gt) {
        *(float4*)&b2f[gt][0] = *(const float4*)(b2 + f * 64 + gt * 16 + quad * 4);
        *(float4*)&w3f[gt][0] = *(const float4*)(w3 + f * 64 + gt * 16 + quad * 4);
    }
    const float b3f = b3[f];

    // ---- 16 chunks of 64 rows ----
    #pragma unroll 1
    for (int c = 0; c < 16; ++c) {
        // one (f-strided) x load: lane holds row rb + c*64 + lane
        const float xv = x[(size_t)(rb + c * 64 + lane) * F_SZ + f];
        float xf[4];
        #pragma unroll
        for (int bt = 0; bt < 4; ++bt)
            xf[bt] = __shfl(xv, bt * 16 + l15, 64);

        // h1 B-fragments: B[k=quad*8+j][n=bt*16+l15]
        short8 hfrag[4][2];
        #pragma unroll
        for (int ks = 0; ks < 2; ++ks)
            #pragma unroll
            for (int bt = 0; bt < 4; ++bt) {
                union { short8 s8; __hip_bfloat162 h2[4]; } o;
                #pragma unroll
                for (int t = 0; t < 4; ++t) {
                    float h0 = fmaxf(fmaf(xf[bt], wk[ks][2 * t],     bk[ks][2 * t]),     0.0f);
                    float h1 = fmaxf(fmaf(xf[bt], wk[ks][2 * t + 1], bk[ks][2 * t + 1]), 0.0f);
                    o.h2[t] = __float22bfloat162_rn(make_float2(h0, h1));
                }
                hfrag[bt][ks] = o.s8;
            }

        // MFMA + epilogue; D layout: g = gt*16 + quad*4 + i, n = bt*16 + l15
        float t[4] = {0.0f, 0.0f, 0.0f, 0.0f};
        #pragma unroll
        for (int gt = 0; gt < 4; ++gt)
            #pragma unroll
            for (int bt = 0; bt < 4; ++bt) {
                floatx4 acc = {b2f[gt][0], b2f[gt][1], b2f[gt][2], b2f[gt][3]};
                acc = __builtin_amdgcn_mfma_f32_16x16x32_bf16(
                    wfrag[gt][0], hfrag[bt][0], acc, 0, 0, 0);
                acc = __builtin_amdgcn_mfma_f32_16x16x32_bf16(
                    wfrag[gt][1], hfrag[bt][1], acc, 0, 0, 0);
                #pragma unroll
                for (int i = 0; i < 4; ++i)
                    t[bt] = fmaf(fmaxf(acc[i], 0.0f), w3f[gt][i], t[bt]);
            }

        // quad-reduce (row = bt*16 + l15), publish per-chunk rows
        #pragma unroll
        for (int bt = 0; bt < 4; ++bt) {
            t[bt] += __shfl_xor(t[bt], 16, 64);
            t[bt] += __shfl_xor(t[bt], 32, 64);
        }
        if (quad == 0) {
            #pragma unroll
            for (int bt = 0; bt < 4; ++bt)
                partial[wv][c * 64 + bt * 16 + l15] = t[bt] + b3f;
        }
    }

    __syncthreads();

    // block reduce over the 4 features, 1 atomic per row
    #pragma unroll
    for (int k = 0; k < 4; ++k) {
        int row = k * 256 + tid;
        float p = partial[0][row] + partial[1][row]
                + partial[2][row] + partial[3][row];
        atomicAdd(&logit[rb + row], p);
    }
}

__global__ __launch_bounds__(256)
void nam_final(const float* __restrict__ logit, const float* __restrict__ bias,
               float* __restrict__ out)
{
    const float bs = bias[0];
    #pragma unroll
    for (int k = 0; k < 4; ++k) {
        int b = blockIdx.x * 1024 + k * 256 + threadIdx.x;
        float s = logit[b] + bs;
        float p = 1.0f / (1.0f + __expf(-s));
        ((float2*)out)[b] = make_float2(1.0f - p, p);
    }
}

extern "C" void kernel_launch(void* const* d_in, const int* in_sizes, int n_in,
                              void* d_out, int out_size, void* d_ws, size_t ws_size,
                              hipStream_t stream)
{
    const float* x    = (const float*)d_in[0];
    const float* w1   = (const float*)d_in[1];
    const float* b1   = (const float*)d_in[2];
    const float* w2   = (const float*)d_in[3];
    const float* b2   = (const float*)d_in[4];
    const float* w3   = (const float*)d_in[5];
    const float* b3   = (const float*)d_in[6];
    const float* bias = (const float*)d_in[7];
    float* out = (float*)d_out;

    unsigned short* ws = (unsigned short*)d_ws;
    float* logit = (float*)(ws + WS_LOG_SHORTS);

    nam_prep<<<dim3(288), dim3(256), 0, stream>>>(w2, ws);
    nam_main<<<dim3(1024), dim3(256), 0, stream>>>(
        x, w1, b1, b2, w3, b3, ws, logit);
    nam_final<<<dim3(B_SZ / 1024), dim3(256), 0, stream>>>(logit, bias, out);
}